// Round 12
// baseline (256.371 us; speedup 1.0000x reference)
//
#include <hip/hip_runtime.h>

#define HID    128
#define SEQ    512
#define BATCH  256
#define DIM    300
#define VOCAB  50000
#define WT_FLOATS 40960  // 160 KB slot for packed-transposed W_ih (needs 38400)

// ---------------------------------------------------------------------------
// Kernel 0 (R4-proven): pack-transpose W_ih [128][300] -> Wt[k4][h][4].
// ---------------------------------------------------------------------------
__global__ __launch_bounds__(256)
void wtrans_kernel(const float* __restrict__ Wih, float* __restrict__ Wt)
{
    int idx = blockIdx.x * 256 + threadIdx.x;
    if (idx < HID * DIM) {
        int h = idx / DIM;
        int k = idx - h * DIM;
        Wt[(k >> 2) * (HID * 4) + h * 4 + (k & 3)] = Wih[idx];
    }
}

// ---------------------------------------------------------------------------
// Kernel A (R11-proven, ~60 µs): proj at 24 waves/CU, 2h x 4r per thread.
// ---------------------------------------------------------------------------
#define ETP 20
#define VT  16
__global__ __launch_bounds__(256)
void proj_fast256(const float* __restrict__ emb,
                  const float* __restrict__ Wt,
                  const float* __restrict__ bih,
                  const float* __restrict__ bhh,
                  float* __restrict__ P)
{
    __shared__ float et[DIM][ETP];   // transposed emb tile: et[k][r], 24 KB
    const int t   = threadIdx.x;     // 0..255
    const int hp  = t & 63;
    const int rg4 = ((t >> 6) & 3) * 4;   // wave-uniform row group {0,4,8,12}
    const int v0  = blockIdx.x * VT;

    {
        const int rr = t >> 4;          // 0..15
        const int kk = t & 15;          // 0..15
        const float* src = emb + (size_t)(v0 + rr) * DIM;
        #pragma unroll
        for (int p = 0; p < 5; ++p) {
            const int f4 = kk + 16 * p; // 0..79
            if (f4 < DIM / 4) {
                const float4 ev = *(const float4*)(src + f4 * 4);
                et[4 * f4 + 0][rr] = ev.x;
                et[4 * f4 + 1][rr] = ev.y;
                et[4 * f4 + 2][rr] = ev.z;
                et[4 * f4 + 3][rr] = ev.w;
            }
        }
    }
    __syncthreads();

    float a00=0.f,a10=0.f,a20=0.f,a30=0.f;
    float a01=0.f,a11=0.f,a21=0.f,a31=0.f;

    const float* wp0 = Wt + hp * 4;
    const float* wp1 = Wt + (hp + 64) * 4;

    for (int k4 = 0; k4 < DIM / 4; ++k4) {
        const float4 wa4 = *(const float4*)(wp0 + k4 * (HID * 4));
        const float4 wb4 = *(const float4*)(wp1 + k4 * (HID * 4));
        #pragma unroll
        for (int jj = 0; jj < 4; ++jj) {
            const float wa = (jj==0)?wa4.x:(jj==1)?wa4.y:(jj==2)?wa4.z:wa4.w;
            const float wb = (jj==0)?wb4.x:(jj==1)?wb4.y:(jj==2)?wb4.z:wb4.w;
            const int k = k4 * 4 + jj;
            const float4 e0 = *(const float4*)(&et[k][rg4]);   // wave-bcast
            a00 = fmaf(wa, e0.x, a00);  a01 = fmaf(wb, e0.x, a01);
            a10 = fmaf(wa, e0.y, a10);  a11 = fmaf(wb, e0.y, a11);
            a20 = fmaf(wa, e0.z, a20);  a21 = fmaf(wb, e0.z, a21);
            a30 = fmaf(wa, e0.w, a30);  a31 = fmaf(wb, e0.w, a31);
        }
    }

    const float bb0 = bih[hp] + bhh[hp];
    const float bb1 = bih[hp + 64] + bhh[hp + 64];
    float* dst = P + (size_t)(v0 + rg4) * HID;
    dst[0*HID + hp] = a00 + bb0;  dst[0*HID + hp + 64] = a01 + bb1;
    dst[1*HID + hp] = a10 + bb0;  dst[1*HID + hp + 64] = a11 + bb1;
    dst[2*HID + hp] = a20 + bb0;  dst[2*HID + hp + 64] = a21 + bb1;
    dst[3*HID + hp] = a30 + bb0;  dst[3*HID + hp + 64] = a31 + bb1;
}

// ---------------------------------------------------------------------------
// Kernel A (fallback, R3-proven): used only if ws_size can't fit Wt + P.
// ---------------------------------------------------------------------------
__global__ __launch_bounds__(128)
void proj_fallback(const float* __restrict__ emb,
                   const float* __restrict__ Wih,
                   const float* __restrict__ bih,
                   const float* __restrict__ bhh,
                   float* __restrict__ P)
{
    __shared__ float et[DIM][ETP];
    const int t  = threadIdx.x;
    const int hp = t & 63;
    const int rg8 = (t >> 6) * 8;
    const int v0 = blockIdx.x * VT;

    #pragma unroll
    for (int r = 0; r < VT; ++r) {
        const float* src = emb + (size_t)(v0 + r) * DIM;
        for (int k = t; k < DIM; k += 128)
            et[k][r] = src[k];
    }
    __syncthreads();

    float a00=0.f,a10=0.f,a20=0.f,a30=0.f,a40=0.f,a50=0.f,a60=0.f,a70=0.f;
    float a01=0.f,a11=0.f,a21=0.f,a31=0.f,a41=0.f,a51=0.f,a61=0.f,a71=0.f;

    const float* w0 = Wih + (size_t)hp * DIM;
    const float* w1 = Wih + (size_t)(hp + 64) * DIM;

    for (int k4 = 0; k4 < DIM / 4; ++k4) {
        const float4 wa4 = *(const float4*)(w0 + k4 * 4);
        const float4 wb4 = *(const float4*)(w1 + k4 * 4);
        #pragma unroll
        for (int jj = 0; jj < 4; ++jj) {
            const float wa = (jj==0)?wa4.x:(jj==1)?wa4.y:(jj==2)?wa4.z:wa4.w;
            const float wb = (jj==0)?wb4.x:(jj==1)?wb4.y:(jj==2)?wb4.z:wb4.w;
            const int k = k4 * 4 + jj;
            const float4 e0 = *(const float4*)(&et[k][rg8]);
            const float4 e1 = *(const float4*)(&et[k][rg8 + 4]);
            a00 = fmaf(wa, e0.x, a00);  a01 = fmaf(wb, e0.x, a01);
            a10 = fmaf(wa, e0.y, a10);  a11 = fmaf(wb, e0.y, a11);
            a20 = fmaf(wa, e0.z, a20);  a21 = fmaf(wb, e0.z, a21);
            a30 = fmaf(wa, e0.w, a30);  a31 = fmaf(wb, e0.w, a31);
            a40 = fmaf(wa, e1.x, a40);  a41 = fmaf(wb, e1.x, a41);
            a50 = fmaf(wa, e1.y, a50);  a51 = fmaf(wb, e1.y, a51);
            a60 = fmaf(wa, e1.z, a60);  a61 = fmaf(wb, e1.z, a61);
            a70 = fmaf(wa, e1.w, a70);  a71 = fmaf(wb, e1.w, a71);
        }
    }

    const float bb0 = bih[hp] + bhh[hp];
    const float bb1 = bih[hp + 64] + bhh[hp + 64];
    float* dst = P + (size_t)(v0 + rg8) * HID;
    dst[0*HID + hp] = a00 + bb0;  dst[0*HID + hp + 64] = a01 + bb1;
    dst[1*HID + hp] = a10 + bb0;  dst[1*HID + hp + 64] = a11 + bb1;
    dst[2*HID + hp] = a20 + bb0;  dst[2*HID + hp + 64] = a21 + bb1;
    dst[3*HID + hp] = a30 + bb0;  dst[3*HID + hp + 64] = a31 + bb1;
    dst[4*HID + hp] = a40 + bb0;  dst[4*HID + hp + 64] = a41 + bb1;
    dst[5*HID + hp] = a50 + bb0;  dst[5*HID + hp + 64] = a51 + bb1;
    dst[6*HID + hp] = a60 + bb0;  dst[6*HID + hp + 64] = a61 + bb1;
    dst[7*HID + hp] = a70 + bb0;  dst[7*HID + hp + 64] = a71 + bb1;
}

// ---------------------------------------------------------------------------
// Kernel B: RNN with quad-cooperative h reads (LDS insts/step: 64 -> 16).
// Lane t: row i = 4*(t>>4)+(t&3); color c=(t>>2)&3 covers k in [32c,32c+32);
// quad slot j=t&3 reads 8 floats (2 b128) of its color's range. Sharing:
// quad_perm broadcasts (0x00/0x55/0xAA/0xFF — slot-explicit, no direction
// ambiguity) feed 32 FMA/lane. Color-reduce: row_ror:8 + row_ror:4 ORBIT
// sums (direction-immune: summing the whole stride-4 orbit of Z16).
// h stored PADDED (+4 floats per 32) -> the 16-address b128 pattern is
// exactly 2-way bank-aliased (free, m136). Chassis (xb chunk staging,
// 1 barrier/step) = R8-proven.
// ---------------------------------------------------------------------------
#define HPAD 140   // 128 + 3*4 padding floats

__global__ __launch_bounds__(512)
void rnn_kernel(const int* __restrict__ x,
                const float* __restrict__ Whh,
                const float* __restrict__ P,
                const float* __restrict__ fcw,
                const float* __restrict__ fcb,
                float* __restrict__ out)
{
    __shared__ float h0b[HPAD];
    __shared__ float h1b[HPAD];
    __shared__ int   toff[SEQ];
    __shared__ float xb[2 * 64 * HID];
    __shared__ float red[HID];

    const int t = threadIdx.x;
    const int b = blockIdx.x;
    const int i = ((t >> 4) << 2) | (t & 3);   // row 0..127 (16/wave)
    const int c = (t >> 2) & 3;                // color: k-range [32c,32c+32)
    const int j = t & 3;                       // quad slot: sub-slice 8j

    const int roff = 36 * c + 8 * j;           // padded addr of k0=32c+8j
    const int hoff = i + ((i >> 5) << 2);      // padded addr of row i

    toff[t] = x[b * SEQ + t] * HID;
    if (t < HID) h0b[t + ((t >> 5) << 2)] = 0.f;

    // W_hh[i][32c + 8k + m], k=0..3, m=0..7  ->  w4[2k + m/4]
    float4 w4[8];
    #pragma unroll
    for (int k = 0; k < 4; ++k) {
        w4[2*k]   = *(const float4*)(Whh + (size_t)i * HID + 32*c + 8*k);
        w4[2*k+1] = *(const float4*)(Whh + (size_t)i * HID + 32*c + 8*k + 4);
    }
    __syncthreads();

#define STAGE(cn) do {                                                        \
        const int w_ = t >> 6, l_ = t & 63;                                   \
        const int base_ = ((cn) & 1) * (64 * HID);                            \
        _Pragma("unroll")                                                     \
        for (int q_ = 0; q_ < 4; ++q_) {                                      \
            const int row_ = w_ * 8 + q_ * 2 + (l_ >> 5);                     \
            const int col_ = (l_ & 31) * 4;                                   \
            const int off_ = toff[(cn) * 64 + row_] + col_;                   \
            const float4 v_ = *(const float4*)(P + off_);                     \
            *(float4*)(&xb[base_ + row_ * HID + col_]) = v_;                  \
        }                                                                     \
    } while (0)

    STAGE(0);
    __syncthreads();

    float hmax = -3.0e38f, hsum = 0.f;

// broadcast quad-slot K's copy of component V (float) via quad_perm
#define QB(V, CTRL) __int_as_float(__builtin_amdgcn_update_dpp(               \
                        0, __float_as_int(V), (CTRL), 0xF, 0xF, true))

#define KSTEP(ACC, EA, EB, KW0, KW1, CTRL) do {                               \
        ACC = fmaf(KW0.x, QB(EA.x, CTRL), ACC);                               \
        ACC = fmaf(KW0.y, QB(EA.y, CTRL), ACC);                               \
        ACC = fmaf(KW0.z, QB(EA.z, CTRL), ACC);                               \
        ACC = fmaf(KW0.w, QB(EA.w, CTRL), ACC);                               \
        ACC = fmaf(KW1.x, QB(EB.x, CTRL), ACC);                               \
        ACC = fmaf(KW1.y, QB(EB.y, CTRL), ACC);                               \
        ACC = fmaf(KW1.z, QB(EB.z, CTRL), ACC);                               \
        ACC = fmaf(KW1.w, QB(EB.w, CTRL), ACC);                               \
    } while (0)

#define STEP(HRD, HWR, XPTR, SOFF) do {                                       \
        const float xt = (XPTR)[(SOFF) * HID];                                \
        const float4 ea = *(const float4*)((HRD) + roff);                     \
        const float4 eb = *(const float4*)((HRD) + roff + 4);                 \
        float ac0 = 0.f, ac1 = 0.f, ac2 = 0.f, ac3 = 0.f;                     \
        KSTEP(ac0, ea, eb, w4[0], w4[1], 0x00);                               \
        KSTEP(ac1, ea, eb, w4[2], w4[3], 0x55);                               \
        KSTEP(ac2, ea, eb, w4[4], w4[5], 0xAA);                               \
        KSTEP(ac3, ea, eb, w4[6], w4[7], 0xFF);                               \
        float s = (ac0 + ac1) + (ac2 + ac3);                                  \
        s += __int_as_float(__builtin_amdgcn_update_dpp(                      \
                 0, __float_as_int(s), 0x128, 0xF, 0xF, true));  /* ror:8 */  \
        s += __int_as_float(__builtin_amdgcn_update_dpp(                      \
                 0, __float_as_int(s), 0x124, 0xF, 0xF, true));  /* ror:4 */  \
        const float z = xt + s;                                               \
        const float e = __builtin_amdgcn_exp2f(z * 2.8853900817779268f);      \
        const float hnew = fmaf(-2.f, __builtin_amdgcn_rcpf(e + 1.f), 1.f);   \
        hmax = fmaxf(hmax, hnew);                                             \
        hsum += hnew;                                                         \
        (HWR)[hoff] = hnew;   /* 4 color-dup lanes: same value, same addr */  \
        __syncthreads();                                                      \
    } while (0)

    for (int cch = 0; cch < 8; ++cch) {
        if (cch < 7) STAGE(cch + 1);
        const float* xp = &xb[(cch & 1) * (64 * HID) + i];
        #pragma unroll 2
        for (int u = 0; u < 32; ++u) {
            STEP(h0b, h1b, xp, u * 2);
            STEP(h1b, h0b, xp, u * 2 + 1);
        }
    }
#undef STEP
#undef KSTEP
#undef QB
#undef STAGE

    // fused pooling + FC (4 color lanes write duplicate value to red[i])
    red[i] = fcw[i] * hmax + fcw[HID + i] * (hsum * (1.f / 512.f));
    __syncthreads();
    if (t < 64) {
        float v = red[t] + red[t + 64];
        #pragma unroll
        for (int m = 32; m >= 1; m >>= 1) v += __shfl_xor(v, m);
        if (t == 0) out[b] = v + fcb[0];
    }
}

// ---------------------------------------------------------------------------
extern "C" void kernel_launch(void* const* d_in, const int* in_sizes, int n_in,
                              void* d_out, int out_size, void* d_ws, size_t ws_size,
                              hipStream_t stream)
{
    const int*   x   = (const int*)  d_in[0];
    const float* emb = (const float*)d_in[1];
    const float* Wih = (const float*)d_in[2];
    const float* Whh = (const float*)d_in[3];
    const float* bih = (const float*)d_in[4];
    const float* bhh = (const float*)d_in[5];
    const float* fcw = (const float*)d_in[6];
    const float* fcb = (const float*)d_in[7];

    float* base = (float*)d_ws;
    const size_t need = (WT_FLOATS + (size_t)VOCAB * HID) * sizeof(float);
    float* P;

    if (ws_size >= need) {
        float* Wt = base;                 // 160 KB, inside d_ws (proven R4)
        P = base + WT_FLOATS;
        wtrans_kernel<<<(HID * DIM + 255) / 256, 256, 0, stream>>>(Wih, Wt);
        proj_fast256<<<VOCAB / VT, 256, 0, stream>>>(emb, Wt, bih, bhh, P);
    } else {
        P = base;
        proj_fallback<<<VOCAB / VT, 128, 0, stream>>>(emb, Wih, bih, bhh, P);
    }

    rnn_kernel<<<BATCH, 512, 0, stream>>>(x, Whh, P, fcw, fcb, (float*)d_out);
}

// Round 13
// 252.862 us; speedup vs baseline: 1.0139x; 1.0139x over previous
//
#include <hip/hip_runtime.h>

#define HID    128
#define SEQ    512
#define BATCH  256
#define DIM    300
#define VOCAB  50000
#define WT_FLOATS 40960  // 160 KB slot for packed-transposed W_ih (needs 38400)

// ---------------------------------------------------------------------------
// Kernel 0 (R4-proven): pack-transpose W_ih [128][300] -> Wt[k4][h][4].
// ---------------------------------------------------------------------------
__global__ __launch_bounds__(256)
void wtrans_kernel(const float* __restrict__ Wih, float* __restrict__ Wt)
{
    int idx = blockIdx.x * 256 + threadIdx.x;
    if (idx < HID * DIM) {
        int h = idx / DIM;
        int k = idx - h * DIM;
        Wt[(k >> 2) * (HID * 4) + h * 4 + (k & 3)] = Wih[idx];
    }
}

// ---------------------------------------------------------------------------
// Kernel A (R11-proven, ~60 µs): proj at 24 waves/CU, 2h x 4r per thread.
// ---------------------------------------------------------------------------
#define ETP 20
#define VT  16
__global__ __launch_bounds__(256)
void proj_fast256(const float* __restrict__ emb,
                  const float* __restrict__ Wt,
                  const float* __restrict__ bih,
                  const float* __restrict__ bhh,
                  float* __restrict__ P)
{
    __shared__ float et[DIM][ETP];   // transposed emb tile: et[k][r], 24 KB
    const int t   = threadIdx.x;     // 0..255
    const int hp  = t & 63;
    const int rg4 = ((t >> 6) & 3) * 4;   // wave-uniform row group {0,4,8,12}
    const int v0  = blockIdx.x * VT;

    {
        const int rr = t >> 4;          // 0..15
        const int kk = t & 15;          // 0..15
        const float* src = emb + (size_t)(v0 + rr) * DIM;
        #pragma unroll
        for (int p = 0; p < 5; ++p) {
            const int f4 = kk + 16 * p; // 0..79
            if (f4 < DIM / 4) {
                const float4 ev = *(const float4*)(src + f4 * 4);
                et[4 * f4 + 0][rr] = ev.x;
                et[4 * f4 + 1][rr] = ev.y;
                et[4 * f4 + 2][rr] = ev.z;
                et[4 * f4 + 3][rr] = ev.w;
            }
        }
    }
    __syncthreads();

    float a00=0.f,a10=0.f,a20=0.f,a30=0.f;
    float a01=0.f,a11=0.f,a21=0.f,a31=0.f;

    const float* wp0 = Wt + hp * 4;
    const float* wp1 = Wt + (hp + 64) * 4;

    for (int k4 = 0; k4 < DIM / 4; ++k4) {
        const float4 wa4 = *(const float4*)(wp0 + k4 * (HID * 4));
        const float4 wb4 = *(const float4*)(wp1 + k4 * (HID * 4));
        #pragma unroll
        for (int jj = 0; jj < 4; ++jj) {
            const float wa = (jj==0)?wa4.x:(jj==1)?wa4.y:(jj==2)?wa4.z:wa4.w;
            const float wb = (jj==0)?wb4.x:(jj==1)?wb4.y:(jj==2)?wb4.z:wb4.w;
            const int k = k4 * 4 + jj;
            const float4 e0 = *(const float4*)(&et[k][rg4]);   // wave-bcast
            a00 = fmaf(wa, e0.x, a00);  a01 = fmaf(wb, e0.x, a01);
            a10 = fmaf(wa, e0.y, a10);  a11 = fmaf(wb, e0.y, a11);
            a20 = fmaf(wa, e0.z, a20);  a21 = fmaf(wb, e0.z, a21);
            a30 = fmaf(wa, e0.w, a30);  a31 = fmaf(wb, e0.w, a31);
        }
    }

    const float bb0 = bih[hp] + bhh[hp];
    const float bb1 = bih[hp + 64] + bhh[hp + 64];
    float* dst = P + (size_t)(v0 + rg4) * HID;
    dst[0*HID + hp] = a00 + bb0;  dst[0*HID + hp + 64] = a01 + bb1;
    dst[1*HID + hp] = a10 + bb0;  dst[1*HID + hp + 64] = a11 + bb1;
    dst[2*HID + hp] = a20 + bb0;  dst[2*HID + hp + 64] = a21 + bb1;
    dst[3*HID + hp] = a30 + bb0;  dst[3*HID + hp + 64] = a31 + bb1;
}

// ---------------------------------------------------------------------------
// Kernel A (fallback, R3-proven): used only if ws_size can't fit Wt + P.
// ---------------------------------------------------------------------------
__global__ __launch_bounds__(128)
void proj_fallback(const float* __restrict__ emb,
                   const float* __restrict__ Wih,
                   const float* __restrict__ bih,
                   const float* __restrict__ bhh,
                   float* __restrict__ P)
{
    __shared__ float et[DIM][ETP];
    const int t  = threadIdx.x;
    const int hp = t & 63;
    const int rg8 = (t >> 6) * 8;
    const int v0 = blockIdx.x * VT;

    #pragma unroll
    for (int r = 0; r < VT; ++r) {
        const float* src = emb + (size_t)(v0 + r) * DIM;
        for (int k = t; k < DIM; k += 128)
            et[k][r] = src[k];
    }
    __syncthreads();

    float a00=0.f,a10=0.f,a20=0.f,a30=0.f,a40=0.f,a50=0.f,a60=0.f,a70=0.f;
    float a01=0.f,a11=0.f,a21=0.f,a31=0.f,a41=0.f,a51=0.f,a61=0.f,a71=0.f;

    const float* w0 = Wih + (size_t)hp * DIM;
    const float* w1 = Wih + (size_t)(hp + 64) * DIM;

    for (int k4 = 0; k4 < DIM / 4; ++k4) {
        const float4 wa4 = *(const float4*)(w0 + k4 * 4);
        const float4 wb4 = *(const float4*)(w1 + k4 * 4);
        #pragma unroll
        for (int jj = 0; jj < 4; ++jj) {
            const float wa = (jj==0)?wa4.x:(jj==1)?wa4.y:(jj==2)?wa4.z:wa4.w;
            const float wb = (jj==0)?wb4.x:(jj==1)?wb4.y:(jj==2)?wb4.z:wb4.w;
            const int k = k4 * 4 + jj;
            const float4 e0 = *(const float4*)(&et[k][rg8]);
            const float4 e1 = *(const float4*)(&et[k][rg8 + 4]);
            a00 = fmaf(wa, e0.x, a00);  a01 = fmaf(wb, e0.x, a01);
            a10 = fmaf(wa, e0.y, a10);  a11 = fmaf(wb, e0.y, a11);
            a20 = fmaf(wa, e0.z, a20);  a21 = fmaf(wb, e0.z, a21);
            a30 = fmaf(wa, e0.w, a30);  a31 = fmaf(wb, e0.w, a31);
            a40 = fmaf(wa, e1.x, a40);  a41 = fmaf(wb, e1.x, a41);
            a50 = fmaf(wa, e1.y, a50);  a51 = fmaf(wb, e1.y, a51);
            a60 = fmaf(wa, e1.z, a60);  a61 = fmaf(wb, e1.z, a61);
            a70 = fmaf(wa, e1.w, a70);  a71 = fmaf(wb, e1.w, a71);
        }
    }

    const float bb0 = bih[hp] + bhh[hp];
    const float bb1 = bih[hp + 64] + bhh[hp + 64];
    float* dst = P + (size_t)(v0 + rg8) * HID;
    dst[0*HID + hp] = a00 + bb0;  dst[0*HID + hp + 64] = a01 + bb1;
    dst[1*HID + hp] = a10 + bb0;  dst[1*HID + hp + 64] = a11 + bb1;
    dst[2*HID + hp] = a20 + bb0;  dst[2*HID + hp + 64] = a21 + bb1;
    dst[3*HID + hp] = a30 + bb0;  dst[3*HID + hp + 64] = a31 + bb1;
    dst[4*HID + hp] = a40 + bb0;  dst[4*HID + hp + 64] = a41 + bb1;
    dst[5*HID + hp] = a50 + bb0;  dst[5*HID + hp + 64] = a51 + bb1;
    dst[6*HID + hp] = a60 + bb0;  dst[6*HID + hp + 64] = a61 + bb1;
    dst[7*HID + hp] = a70 + bb0;  dst[7*HID + hp + 64] = a71 + bb1;
}

// ---------------------------------------------------------------------------
// Kernel B: RNN, R8 chassis with h stored as BF16 in LDS.
// Thread (i=t>>2, kq=t&3): reads its 32 h values as 4 ds_read_b128 (was 8)
// -> LDS pipe (the measured bottleneck: 64 insts x 12 cyc = 774 cyc/step,
// ~100% busy) halves to ~410 cyc. Unpack bf16->f32 is 1 VALU/value
// (<<16 / &0xFFFF0000). W stays fp32 in VGPRs; accumulation fp32; only h
// quantized (RTNE) -> predicted output error ~2e-3 vs 1.35e-2 threshold.
// Rotation pj=(j+kq)&3 -> kq0/kq2 read disjoint bank quads (R3-proven).
// ---------------------------------------------------------------------------
__device__ __forceinline__ float quad_sum(float v)
{
    int x1 = __builtin_amdgcn_update_dpp(0, __float_as_int(v), 0xB1, 0xF, 0xF, true);
    v += __int_as_float(x1);
    int x2 = __builtin_amdgcn_update_dpp(0, __float_as_int(v), 0x4E, 0xF, 0xF, true);
    v += __int_as_float(x2);
    return v;
}

__global__ __launch_bounds__(512)
void rnn_kernel(const int* __restrict__ x,
                const float* __restrict__ Whh,
                const float* __restrict__ P,
                const float* __restrict__ fcw,
                const float* __restrict__ fcb,
                float* __restrict__ out)
{
    __shared__ __align__(16) unsigned short h0b[HID];   // bf16 h, 256 B
    __shared__ __align__(16) unsigned short h1b[HID];
    __shared__ int   toff[SEQ];
    __shared__ float xb[2 * 64 * HID];
    __shared__ float red[HID];

    const int t  = threadIdx.x;
    const int b  = blockIdx.x;
    const int i  = t >> 2;
    const int kq = t & 3;

    toff[t] = x[b * SEQ + t] * HID;
    if (t < HID) h0b[t] = 0;   // bf16 zero

    // W_hh[i][kq*32 + pj*8 .. +8], pj=(j+kq)&3 rotation (conflict-free reads)
    float w[32];
    #pragma unroll
    for (int j = 0; j < 4; ++j) {
        const int pj = (j + kq) & 3;
        const float4 vA = *(const float4*)(Whh + (size_t)i * HID + kq * 32 + pj * 8);
        const float4 vB = *(const float4*)(Whh + (size_t)i * HID + kq * 32 + pj * 8 + 4);
        w[j*8+0]=vA.x; w[j*8+1]=vA.y; w[j*8+2]=vA.z; w[j*8+3]=vA.w;
        w[j*8+4]=vB.x; w[j*8+5]=vB.y; w[j*8+6]=vB.z; w[j*8+7]=vB.w;
    }
    __syncthreads();

#define STAGE(cn) do {                                                        \
        const int w_ = t >> 6, l_ = t & 63;                                   \
        const int base_ = ((cn) & 1) * (64 * HID);                            \
        _Pragma("unroll")                                                     \
        for (int q_ = 0; q_ < 4; ++q_) {                                      \
            const int row_ = w_ * 8 + q_ * 2 + (l_ >> 5);                     \
            const int col_ = (l_ & 31) * 4;                                   \
            const int off_ = toff[(cn) * 64 + row_] + col_;                   \
            const float4 v_ = *(const float4*)(P + off_);                     \
            *(float4*)(&xb[base_ + row_ * HID + col_]) = v_;                  \
        }                                                                     \
    } while (0)

    STAGE(0);
    __syncthreads();

    float hmax = -3.0e38f, hsum = 0.f;

#define LOF(U) __int_as_float((int)((U) << 16))
#define HIF(U) __int_as_float((int)((U) & 0xFFFF0000u))

#define JBLK(HRD, J, ACA, ACB) do {                                           \
        const int pj_ = ((J) + kq) & 3;                                       \
        const uint4 q_ = *(const uint4*)((HRD) + kq * 32 + pj_ * 8);          \
        ACA = fmaf(w[(J)*8+0], LOF(q_.x), ACA);                               \
        ACB = fmaf(w[(J)*8+1], HIF(q_.x), ACB);                               \
        ACA = fmaf(w[(J)*8+2], LOF(q_.y), ACA);                               \
        ACB = fmaf(w[(J)*8+3], HIF(q_.y), ACB);                               \
        ACA = fmaf(w[(J)*8+4], LOF(q_.z), ACA);                               \
        ACB = fmaf(w[(J)*8+5], HIF(q_.z), ACB);                               \
        ACA = fmaf(w[(J)*8+6], LOF(q_.w), ACA);                               \
        ACB = fmaf(w[(J)*8+7], HIF(q_.w), ACB);                               \
    } while (0)

#define STEP(HRD, HWR, XPTR, SOFF) do {                                       \
        const float xt = (XPTR)[(SOFF) * HID];                                \
        float ac0=0.f,ac1=0.f,ac2=0.f,ac3=0.f,ac4=0.f,ac5=0.f,ac6=0.f,ac7=0.f;\
        JBLK(HRD, 0, ac0, ac1);                                               \
        JBLK(HRD, 1, ac2, ac3);                                               \
        JBLK(HRD, 2, ac4, ac5);                                               \
        JBLK(HRD, 3, ac6, ac7);                                               \
        float acc = ((ac0+ac1)+(ac2+ac3)) + ((ac4+ac5)+(ac6+ac7));            \
        acc = quad_sum(acc);                                                  \
        const float z = xt + acc;                                             \
        const float e = __builtin_amdgcn_exp2f(z * 2.8853900817779268f);      \
        const float hnew = fmaf(-2.f, __builtin_amdgcn_rcpf(e + 1.f), 1.f);   \
        hmax = fmaxf(hmax, hnew);                                             \
        hsum += hnew;                                                         \
        unsigned u_ = __float_as_uint(hnew);                                  \
        u_ = (u_ + 0x7FFFu + ((u_ >> 16) & 1u)) >> 16;   /* RTNE bf16 */      \
        (HWR)[i] = (unsigned short)u_;   /* 4 dup lanes: same val+addr */     \
        __syncthreads();                                                      \
    } while (0)

    for (int c = 0; c < 8; ++c) {
        if (c < 7) STAGE(c + 1);
        const float* xp = &xb[(c & 1) * (64 * HID) + i];
        #pragma unroll 4
        for (int u = 0; u < 32; ++u) {
            STEP(h0b, h1b, xp, u * 2);
            STEP(h1b, h0b, xp, u * 2 + 1);
        }
    }
#undef STEP
#undef JBLK
#undef LOF
#undef HIF
#undef STAGE

    if (kq == 0)
        red[i] = fcw[i] * hmax + fcw[HID + i] * (hsum * (1.f / 512.f));
    __syncthreads();
    if (t < 64) {
        float v = red[t] + red[t + 64];
        #pragma unroll
        for (int m = 32; m >= 1; m >>= 1) v += __shfl_xor(v, m);
        if (t == 0) out[b] = v + fcb[0];
    }
}

// ---------------------------------------------------------------------------
extern "C" void kernel_launch(void* const* d_in, const int* in_sizes, int n_in,
                              void* d_out, int out_size, void* d_ws, size_t ws_size,
                              hipStream_t stream)
{
    const int*   x   = (const int*)  d_in[0];
    const float* emb = (const float*)d_in[1];
    const float* Wih = (const float*)d_in[2];
    const float* Whh = (const float*)d_in[3];
    const float* bih = (const float*)d_in[4];
    const float* bhh = (const float*)d_in[5];
    const float* fcw = (const float*)d_in[6];
    const float* fcb = (const float*)d_in[7];

    float* base = (float*)d_ws;
    const size_t need = (WT_FLOATS + (size_t)VOCAB * HID) * sizeof(float);
    float* P;

    if (ws_size >= need) {
        float* Wt = base;                 // 160 KB, inside d_ws (proven R4)
        P = base + WT_FLOATS;
        wtrans_kernel<<<(HID * DIM + 255) / 256, 256, 0, stream>>>(Wih, Wt);
        proj_fast256<<<VOCAB / VT, 256, 0, stream>>>(emb, Wt, bih, bhh, P);
    } else {
        P = base;
        proj_fallback<<<VOCAB / VT, 128, 0, stream>>>(emb, Wih, bih, bhh, P);
    }

    rnn_kernel<<<BATCH, 512, 0, stream>>>(x, Whh, P, fcw, fcb, (float*)d_out);
}

// Round 14
// 228.053 us; speedup vs baseline: 1.1242x; 1.1088x over previous
//
#include <hip/hip_runtime.h>

#define HID    128
#define SEQ    512
#define BATCH  256
#define DIM    300
#define VOCAB  50000

typedef short bf16x8 __attribute__((ext_vector_type(8)));   // 8 bf16 = 4 VGPR
typedef float f32x4  __attribute__((ext_vector_type(4)));

// ---------------------------------------------------------------------------
// Kernel A: proj via MFMA bf16. P[v][h] = emb[v,:]·W_ih[h,:] + b_ih + b_hh.
// Block: 512 thr (8 waves), 64 vocab rows x 128 h. Stage emb-tile + full W
// as bf16 (RTNE) into LDS, K padded 300->320 with zeros. Wave w: m-tile
// w>>1 (16 rows), n-half w&1 (4 n-tiles). 10 K-steps x (1 A-frag + 4
// B-frags ds_read_b128 + 4 MFMA). LDS row stride 328 bf16 (656B) to break
// power-of-2 bank alias. Layout: A row=lane&15, k=(lane>>4)*8+e;
// B col=lane&15, same k; D col=lane&15, row=(lane>>4)*4+reg (m89).
// ---------------------------------------------------------------------------
#define KP   320        // padded K (10 x 32)
#define LST  328        // LDS row stride in bf16 (656 B, 16B-aligned)

__device__ __forceinline__ unsigned bf16_rtne(float v)
{
    unsigned u = __float_as_uint(v);
    return (u + 0x7FFFu + ((u >> 16) & 1u)) >> 16;
}

__global__ __launch_bounds__(512)
void proj_mfma(const float* __restrict__ emb,
               const float* __restrict__ Wih,
               const float* __restrict__ bih,
               const float* __restrict__ bhh,
               float* __restrict__ P)
{
    __shared__ unsigned short At[64 * LST];    // emb tile, bf16
    __shared__ unsigned short Bt[128 * LST];   // full W_ih, bf16

    const int t  = threadIdx.x;
    const int v0 = blockIdx.x * 64;

    // ---- stage emb tile (64 rows x 40 chunks of 8) ----
    for (int c = t; c < 64 * 40; c += 512) {
        const int row = c / 40;
        const int ch  = c - row * 40;
        int grow = v0 + row; if (grow > VOCAB - 1) grow = VOCAB - 1;
        const float* src = emb + (size_t)grow * DIM;
        const int k0 = ch * 8;
        unsigned p0, p1, p2, p3;
        if (k0 + 8 <= DIM) {
            const float4 a = *(const float4*)(src + k0);
            const float4 b = *(const float4*)(src + k0 + 4);
            p0 = bf16_rtne(a.x) | (bf16_rtne(a.y) << 16);
            p1 = bf16_rtne(a.z) | (bf16_rtne(a.w) << 16);
            p2 = bf16_rtne(b.x) | (bf16_rtne(b.y) << 16);
            p3 = bf16_rtne(b.z) | (bf16_rtne(b.w) << 16);
        } else {
            unsigned q[8];
            #pragma unroll
            for (int e = 0; e < 8; ++e) {
                const int k = k0 + e;
                q[e] = (k < DIM) ? bf16_rtne(src[k]) : 0u;
            }
            p0 = q[0] | (q[1] << 16);  p1 = q[2] | (q[3] << 16);
            p2 = q[4] | (q[5] << 16);  p3 = q[6] | (q[7] << 16);
        }
        uint4 o = {p0, p1, p2, p3};
        *(uint4*)(&At[row * LST + k0]) = o;
    }

    // ---- stage W (128 rows x 40 chunks of 8) ----
    for (int c = t; c < 128 * 40; c += 512) {
        const int row = c / 40;
        const int ch  = c - row * 40;
        const float* src = Wih + (size_t)row * DIM;
        const int k0 = ch * 8;
        unsigned p0, p1, p2, p3;
        if (k0 + 8 <= DIM) {
            const float4 a = *(const float4*)(src + k0);
            const float4 b = *(const float4*)(src + k0 + 4);
            p0 = bf16_rtne(a.x) | (bf16_rtne(a.y) << 16);
            p1 = bf16_rtne(a.z) | (bf16_rtne(a.w) << 16);
            p2 = bf16_rtne(b.x) | (bf16_rtne(b.y) << 16);
            p3 = bf16_rtne(b.z) | (bf16_rtne(b.w) << 16);
        } else {
            unsigned q[8];
            #pragma unroll
            for (int e = 0; e < 8; ++e) {
                const int k = k0 + e;
                q[e] = (k < DIM) ? bf16_rtne(src[k]) : 0u;
            }
            p0 = q[0] | (q[1] << 16);  p1 = q[2] | (q[3] << 16);
            p2 = q[4] | (q[5] << 16);  p3 = q[6] | (q[7] << 16);
        }
        uint4 o = {p0, p1, p2, p3};
        *(uint4*)(&Bt[row * LST + k0]) = o;
    }
    __syncthreads();

    // ---- MFMA k-loop ----
    const int lane = t & 63;
    const int w    = t >> 6;          // wave 0..7
    const int mt   = w >> 1;          // m-tile 0..3 (16 vocab rows)
    const int nh   = w & 1;           // n-half (4 n-tiles of 16 h)
    const int lm   = lane & 15;
    const int kg   = lane >> 4;       // k-group 0..3

    f32x4 acc0 = {0.f,0.f,0.f,0.f}, acc1 = {0.f,0.f,0.f,0.f};
    f32x4 acc2 = {0.f,0.f,0.f,0.f}, acc3 = {0.f,0.f,0.f,0.f};

    const unsigned short* arow = &At[(mt * 16 + lm) * LST + kg * 8];
    const unsigned short* brow = &Bt[(nh * 64 + lm) * LST + kg * 8];

    for (int k0 = 0; k0 < KP; k0 += 32) {
        const bf16x8 af = *(const bf16x8*)(arow + k0);
        const bf16x8 b0 = *(const bf16x8*)(brow + k0);
        const bf16x8 b1 = *(const bf16x8*)(brow + 16 * LST + k0);
        const bf16x8 b2 = *(const bf16x8*)(brow + 32 * LST + k0);
        const bf16x8 b3 = *(const bf16x8*)(brow + 48 * LST + k0);
        acc0 = __builtin_amdgcn_mfma_f32_16x16x32_bf16(af, b0, acc0, 0, 0, 0);
        acc1 = __builtin_amdgcn_mfma_f32_16x16x32_bf16(af, b1, acc1, 0, 0, 0);
        acc2 = __builtin_amdgcn_mfma_f32_16x16x32_bf16(af, b2, acc2, 0, 0, 0);
        acc3 = __builtin_amdgcn_mfma_f32_16x16x32_bf16(af, b3, acc3, 0, 0, 0);
    }

    // ---- store: D col=lane&15, row=(lane>>4)*4+reg ----
    const int rbase = v0 + mt * 16 + kg * 4;
    #pragma unroll
    for (int nt = 0; nt < 4; ++nt) {
        const int h = nh * 64 + nt * 16 + lm;
        const float bb = bih[h] + bhh[h];
        const f32x4 a = (nt == 0) ? acc0 : (nt == 1) ? acc1 : (nt == 2) ? acc2 : acc3;
        #pragma unroll
        for (int r = 0; r < 4; ++r) {
            const int row = rbase + r;
            if (row < VOCAB) P[(size_t)row * HID + h] = a[r] + bb;
        }
    }
}

// ---------------------------------------------------------------------------
// Kernel B: RNN — BYTE-IDENTICAL to R8 (164-166 µs measured, absmax 0).
// ---------------------------------------------------------------------------
__device__ __forceinline__ float quad_sum(float v)
{
    int x1 = __builtin_amdgcn_update_dpp(0, __float_as_int(v), 0xB1, 0xF, 0xF, true);
    v += __int_as_float(x1);
    int x2 = __builtin_amdgcn_update_dpp(0, __float_as_int(v), 0x4E, 0xF, 0xF, true);
    v += __int_as_float(x2);
    return v;
}

__global__ __launch_bounds__(512)
void rnn_kernel(const int* __restrict__ x,
                const float* __restrict__ Whh,
                const float* __restrict__ P,
                const float* __restrict__ fcw,
                const float* __restrict__ fcb,
                float* __restrict__ out)
{
    __shared__ float h0b[HID];
    __shared__ float h1b[HID];
    __shared__ int   toff[SEQ];
    __shared__ float xb[2 * 64 * HID];
    __shared__ float red[HID];

    const int t  = threadIdx.x;
    const int b  = blockIdx.x;
    const int i  = t >> 2;
    const int kq = t & 3;

    toff[t] = x[b * SEQ + t] * HID;
    if (t < HID) h0b[t] = 0.f;

    float4 w[8];
    #pragma unroll
    for (int j = 0; j < 8; ++j) {
        const int pj = (j + 2 * kq) & 7;
        w[j] = *(const float4*)(Whh + (size_t)i * HID + kq * 32 + pj * 4);
    }
    __syncthreads();

#define STAGE(cn) do {                                                        \
        const int w_ = t >> 6, l_ = t & 63;                                   \
        const int base_ = ((cn) & 1) * (64 * HID);                            \
        _Pragma("unroll")                                                     \
        for (int q_ = 0; q_ < 4; ++q_) {                                      \
            const int row_ = w_ * 8 + q_ * 2 + (l_ >> 5);                     \
            const int col_ = (l_ & 31) * 4;                                   \
            const int off_ = toff[(cn) * 64 + row_] + col_;                   \
            const float4 v_ = *(const float4*)(P + off_);                     \
            *(float4*)(&xb[base_ + row_ * HID + col_]) = v_;                  \
        }                                                                     \
    } while (0)

    STAGE(0);
    __syncthreads();

    float hmax = -3.0e38f, hsum = 0.f;

#define STEP(HRD, HWR, XPTR, SOFF) do {                                       \
        const float xt = (XPTR)[(SOFF) * HID];                                \
        float ac0=0.f,ac1=0.f,ac2=0.f,ac3=0.f,ac4=0.f,ac5=0.f,ac6=0.f,ac7=0.f;\
        _Pragma("unroll")                                                     \
        for (int j = 0; j < 8; ++j) {                                         \
            const int pj = (j + 2 * kq) & 7;                                  \
            const float4 h4 = *(const float4*)((HRD) + kq * 32 + pj * 4);     \
            float* ap = (j==0)?&ac0:(j==1)?&ac1:(j==2)?&ac2:(j==3)?&ac3       \
                       :(j==4)?&ac4:(j==5)?&ac5:(j==6)?&ac6:&ac7;             \
            *ap = fmaf(w[j].x, h4.x, *ap);                                    \
            *ap = fmaf(w[j].y, h4.y, *ap);                                    \
            *ap = fmaf(w[j].z, h4.z, *ap);                                    \
            *ap = fmaf(w[j].w, h4.w, *ap);                                    \
        }                                                                     \
        float acc = ((ac0+ac1)+(ac2+ac3)) + ((ac4+ac5)+(ac6+ac7));            \
        acc = quad_sum(acc);                                                  \
        const float z = xt + acc;                                             \
        const float e = __builtin_amdgcn_exp2f(z * 2.8853900817779268f);      \
        const float hnew = fmaf(-2.f, __builtin_amdgcn_rcpf(e + 1.f), 1.f);   \
        hmax = fmaxf(hmax, hnew);                                             \
        hsum += hnew;                                                         \
        (HWR)[i] = hnew;                                                      \
        __syncthreads();                                                      \
    } while (0)

    for (int c = 0; c < 8; ++c) {
        if (c < 7) STAGE(c + 1);
        const float* xp = &xb[(c & 1) * (64 * HID) + i];
        #pragma unroll 4
        for (int u = 0; u < 32; ++u) {
            STEP(h0b, h1b, xp, u * 2);
            STEP(h1b, h0b, xp, u * 2 + 1);
        }
    }
#undef STEP
#undef STAGE

    if (kq == 0)
        red[i] = fcw[i] * hmax + fcw[HID + i] * (hsum * (1.f / 512.f));
    __syncthreads();
    if (t < 64) {
        float v = red[t] + red[t + 64];
        #pragma unroll
        for (int m = 32; m >= 1; m >>= 1) v += __shfl_xor(v, m);
        if (t == 0) out[b] = v + fcb[0];
    }
}

// ---------------------------------------------------------------------------
extern "C" void kernel_launch(void* const* d_in, const int* in_sizes, int n_in,
                              void* d_out, int out_size, void* d_ws, size_t ws_size,
                              hipStream_t stream)
{
    const int*   x   = (const int*)  d_in[0];
    const float* emb = (const float*)d_in[1];
    const float* Wih = (const float*)d_in[2];
    const float* Whh = (const float*)d_in[3];
    const float* bih = (const float*)d_in[4];
    const float* bhh = (const float*)d_in[5];
    const float* fcw = (const float*)d_in[6];
    const float* fcb = (const float*)d_in[7];

    float* P = (float*)d_ws;   // exactly VOCAB*HID*4 = 25.6 MB (R1-proven)

    proj_mfma<<<(VOCAB + 63) / 64, 512, 0, stream>>>(emb, Wih, bih, bhh, P);
    rnn_kernel<<<BATCH, 512, 0, stream>>>(x, Whh, P, fcw, fcb, (float*)d_out);
}

// Round 15
// 197.845 us; speedup vs baseline: 1.2958x; 1.1527x over previous
//
#include <hip/hip_runtime.h>

#define HID    128
#define SEQ    512
#define BATCH  256
#define DIM    300
#define VOCAB  50000

typedef short bf16x8 __attribute__((ext_vector_type(8)));   // 8 bf16 = 4 VGPR
typedef float f32x4  __attribute__((ext_vector_type(4)));

#define KP     320      // padded K (10 x 32)
#define LST    328      // LDS row stride in bf16 (656 B, 16B-aligned)
#define TROWS  32       // vocab rows per tile
#define NTILES ((VOCAB + TROWS - 1) / TROWS)   // 1563

__device__ __forceinline__ unsigned bf16_rtne(float v)
{
    unsigned u = __float_as_uint(v);
    return (u + 0x7FFFu + ((u >> 16) & 1u)) >> 16;
}

// ---------------------------------------------------------------------------
// Kernel A: PERSISTENT MFMA proj. grid=256 (1 block/CU). Each block:
//  - stages W_ih -> bf16 LDS ONCE (was: every one of 782 blocks),
//  - loops over its ~6 tiles of 32 vocab rows with DOUBLE-BUFFERED emb
//    staging (stage r+1 issued before MFMA of r -> HBM latency + stores
//    hide under compute; 1 barrier/tile).
// Fragment addressing byte-identical to R14 (absmax 0.0039-verified):
// A row=lane&15,k=(lane>>4)*8+e; B col=lane&15; D col=lane&15,
// row=(lane>>4)*4+reg. Wave w: m-tile=w>>2, n-pair=w&3.
// ---------------------------------------------------------------------------
__global__ __launch_bounds__(512)
void proj_persist(const float* __restrict__ emb,
                  const float* __restrict__ Wih,
                  const float* __restrict__ bih,
                  const float* __restrict__ bhh,
                  float* __restrict__ P)
{
    __shared__ unsigned short Bt[128 * LST];       // W_ih bf16 (84 KB)
    __shared__ unsigned short At[2 * TROWS * LST]; // emb dbuf (2 x 21 KB)

    const int t   = threadIdx.x;
    const int bid = blockIdx.x;

    // ---- stage W once (128 rows x 40 chunks of 8) ----
    for (int c = t; c < 128 * 40; c += 512) {
        const int row = c / 40;
        const int ch  = c - row * 40;
        const float* src = Wih + (size_t)row * DIM;
        const int k0 = ch * 8;
        unsigned p0, p1, p2, p3;
        if (k0 + 8 <= DIM) {
            const float4 a = *(const float4*)(src + k0);
            const float4 b = *(const float4*)(src + k0 + 4);
            p0 = bf16_rtne(a.x) | (bf16_rtne(a.y) << 16);
            p1 = bf16_rtne(a.z) | (bf16_rtne(a.w) << 16);
            p2 = bf16_rtne(b.x) | (bf16_rtne(b.y) << 16);
            p3 = bf16_rtne(b.z) | (bf16_rtne(b.w) << 16);
        } else {
            unsigned q[8];
            #pragma unroll
            for (int e = 0; e < 8; ++e) {
                const int k = k0 + e;
                q[e] = (k < DIM) ? bf16_rtne(src[k]) : 0u;
            }
            p0 = q[0] | (q[1] << 16);  p1 = q[2] | (q[3] << 16);
            p2 = q[4] | (q[5] << 16);  p3 = q[6] | (q[7] << 16);
        }
        uint4 o = {p0, p1, p2, p3};
        *(uint4*)(&Bt[row * LST + k0]) = o;
    }

// stage emb tile `tl` (TROWS rows) into At half `bf`
#define STAGE_EMB(tl, bf) do {                                                \
        const int v0_ = (tl) * TROWS;                                         \
        for (int c = t; c < TROWS * 40; c += 512) {                           \
            const int row = c / 40;                                           \
            const int ch  = c - row * 40;                                     \
            int grow = v0_ + row; if (grow > VOCAB - 1) grow = VOCAB - 1;     \
            const float* src = emb + (size_t)grow * DIM;                      \
            const int k0 = ch * 8;                                            \
            unsigned p0, p1, p2, p3;                                          \
            if (k0 + 8 <= DIM) {                                              \
                const float4 a = *(const float4*)(src + k0);                  \
                const float4 b = *(const float4*)(src + k0 + 4);              \
                p0 = bf16_rtne(a.x) | (bf16_rtne(a.y) << 16);                 \
                p1 = bf16_rtne(a.z) | (bf16_rtne(a.w) << 16);                 \
                p2 = bf16_rtne(b.x) | (bf16_rtne(b.y) << 16);                 \
                p3 = bf16_rtne(b.z) | (bf16_rtne(b.w) << 16);                 \
            } else {                                                          \
                unsigned q[8];                                                \
                _Pragma("unroll")                                             \
                for (int e = 0; e < 8; ++e) {                                 \
                    const int k = k0 + e;                                     \
                    q[e] = (k < DIM) ? bf16_rtne(src[k]) : 0u;                \
                }                                                             \
                p0 = q[0] | (q[1] << 16);  p1 = q[2] | (q[3] << 16);          \
                p2 = q[4] | (q[5] << 16);  p3 = q[6] | (q[7] << 16);          \
            }                                                                 \
            uint4 o = {p0, p1, p2, p3};                                       \
            *(uint4*)(&At[(bf) * (TROWS * LST) + row * LST + k0]) = o;        \
        }                                                                     \
    } while (0)

    const int lane = t & 63;
    const int w    = t >> 6;          // wave 0..7
    const int mt   = w >> 2;          // m-tile 0..1 (16 vocab rows)
    const int np   = w & 3;           // n-pair: n-tiles 2np, 2np+1
    const int lm   = lane & 15;
    const int kg   = lane >> 4;       // k-group 0..3

    STAGE_EMB(bid, 0);
    __syncthreads();

    int buf = 0;
    for (int tile = bid; tile < NTILES; tile += 256) {
        // issue next tile's staging first (overlaps MFMA below)
        if (tile + 256 < NTILES) STAGE_EMB(tile + 256, buf ^ 1);

        // ---- MFMA: 2 n-tiles per wave, 10 k-steps ----
        const unsigned short* arow = &At[buf * (TROWS * LST)
                                         + (mt * 16 + lm) * LST + kg * 8];
        const unsigned short* brow = &Bt[(np * 32 + lm) * LST + kg * 8];

        f32x4 acc0 = {0.f,0.f,0.f,0.f}, acc1 = {0.f,0.f,0.f,0.f};
        #pragma unroll
        for (int k0 = 0; k0 < KP; k0 += 32) {
            const bf16x8 af = *(const bf16x8*)(arow + k0);
            const bf16x8 b0 = *(const bf16x8*)(brow + k0);
            const bf16x8 b1 = *(const bf16x8*)(brow + 16 * LST + k0);
            acc0 = __builtin_amdgcn_mfma_f32_16x16x32_bf16(af, b0, acc0, 0, 0, 0);
            acc1 = __builtin_amdgcn_mfma_f32_16x16x32_bf16(af, b1, acc1, 0, 0, 0);
        }

        // ---- store ----
        const int rbase = tile * TROWS + mt * 16 + kg * 4;
        #pragma unroll
        for (int nt2 = 0; nt2 < 2; ++nt2) {
            const int h = (np * 2 + nt2) * 16 + lm;
            const float bb = bih[h] + bhh[h];
            const f32x4 a = nt2 ? acc1 : acc0;
            #pragma unroll
            for (int r = 0; r < 4; ++r) {
                const int row = rbase + r;
                if (row < VOCAB) P[(size_t)row * HID + h] = a[r] + bb;
            }
        }

        __syncthreads();   // next buffer visible; current safe to overwrite
        buf ^= 1;
    }
#undef STAGE_EMB
}

// ---------------------------------------------------------------------------
// Kernel B: RNN — BYTE-IDENTICAL to R8 (164-166 µs measured).
// ---------------------------------------------------------------------------
__device__ __forceinline__ float quad_sum(float v)
{
    int x1 = __builtin_amdgcn_update_dpp(0, __float_as_int(v), 0xB1, 0xF, 0xF, true);
    v += __int_as_float(x1);
    int x2 = __builtin_amdgcn_update_dpp(0, __float_as_int(v), 0x4E, 0xF, 0xF, true);
    v += __int_as_float(x2);
    return v;
}

__global__ __launch_bounds__(512)
void rnn_kernel(const int* __restrict__ x,
                const float* __restrict__ Whh,
                const float* __restrict__ P,
                const float* __restrict__ fcw,
                const float* __restrict__ fcb,
                float* __restrict__ out)
{
    __shared__ float h0b[HID];
    __shared__ float h1b[HID];
    __shared__ int   toff[SEQ];
    __shared__ float xb[2 * 64 * HID];
    __shared__ float red[HID];

    const int t  = threadIdx.x;
    const int b  = blockIdx.x;
    const int i  = t >> 2;
    const int kq = t & 3;

    toff[t] = x[b * SEQ + t] * HID;
    if (t < HID) h0b[t] = 0.f;

    float4 w[8];
    #pragma unroll
    for (int j = 0; j < 8; ++j) {
        const int pj = (j + 2 * kq) & 7;
        w[j] = *(const float4*)(Whh + (size_t)i * HID + kq * 32 + pj * 4);
    }
    __syncthreads();

#define STAGE(cn) do {                                                        \
        const int w_ = t >> 6, l_ = t & 63;                                   \
        const int base_ = ((cn) & 1) * (64 * HID);                            \
        _Pragma("unroll")                                                     \
        for (int q_ = 0; q_ < 4; ++q_) {                                      \
            const int row_ = w_ * 8 + q_ * 2 + (l_ >> 5);                     \
            const int col_ = (l_ & 31) * 4;                                   \
            const int off_ = toff[(cn) * 64 + row_] + col_;                   \
            const float4 v_ = *(const float4*)(P + off_);                     \
            *(float4*)(&xb[base_ + row_ * HID + col_]) = v_;                  \
        }                                                                     \
    } while (0)

    STAGE(0);
    __syncthreads();

    float hmax = -3.0e38f, hsum = 0.f;

#define STEP(HRD, HWR, XPTR, SOFF) do {                                       \
        const float xt = (XPTR)[(SOFF) * HID];                                \
        float ac0=0.f,ac1=0.f,ac2=0.f,ac3=0.f,ac4=0.f,ac5=0.f,ac6=0.f,ac7=0.f;\
        _Pragma("unroll")                                                     \
        for (int j = 0; j < 8; ++j) {                                         \
            const int pj = (j + 2 * kq) & 7;                                  \
            const float4 h4 = *(const float4*)((HRD) + kq * 32 + pj * 4);     \
            float* ap = (j==0)?&ac0:(j==1)?&ac1:(j==2)?&ac2:(j==3)?&ac3       \
                       :(j==4)?&ac4:(j==5)?&ac5:(j==6)?&ac6:&ac7;             \
            *ap = fmaf(w[j].x, h4.x, *ap);                                    \
            *ap = fmaf(w[j].y, h4.y, *ap);                                    \
            *ap = fmaf(w[j].z, h4.z, *ap);                                    \
            *ap = fmaf(w[j].w, h4.w, *ap);                                    \
        }                                                                     \
        float acc = ((ac0+ac1)+(ac2+ac3)) + ((ac4+ac5)+(ac6+ac7));            \
        acc = quad_sum(acc);                                                  \
        const float z = xt + acc;                                             \
        const float e = __builtin_amdgcn_exp2f(z * 2.8853900817779268f);      \
        const float hnew = fmaf(-2.f, __builtin_amdgcn_rcpf(e + 1.f), 1.f);   \
        hmax = fmaxf(hmax, hnew);                                             \
        hsum += hnew;                                                         \
        (HWR)[i] = hnew;                                                      \
        __syncthreads();                                                      \
    } while (0)

    for (int c = 0; c < 8; ++c) {
        if (c < 7) STAGE(c + 1);
        const float* xp = &xb[(c & 1) * (64 * HID) + i];
        #pragma unroll 4
        for (int u = 0; u < 32; ++u) {
            STEP(h0b, h1b, xp, u * 2);
            STEP(h1b, h0b, xp, u * 2 + 1);
        }
    }
#undef STEP
#undef STAGE

    if (kq == 0)
        red[i] = fcw[i] * hmax + fcw[HID + i] * (hsum * (1.f / 512.f));
    __syncthreads();
    if (t < 64) {
        float v = red[t] + red[t + 64];
        #pragma unroll
        for (int m = 32; m >= 1; m >>= 1) v += __shfl_xor(v, m);
        if (t == 0) out[b] = v + fcb[0];
    }
}

// ---------------------------------------------------------------------------
extern "C" void kernel_launch(void* const* d_in, const int* in_sizes, int n_in,
                              void* d_out, int out_size, void* d_ws, size_t ws_size,
                              hipStream_t stream)
{
    const int*   x   = (const int*)  d_in[0];
    const float* emb = (const float*)d_in[1];
    const float* Wih = (const float*)d_in[2];
    const float* Whh = (const float*)d_in[3];
    const float* bih = (const float*)d_in[4];
    const float* bhh = (const float*)d_in[5];
    const float* fcw = (const float*)d_in[6];
    const float* fcb = (const float*)d_in[7];

    float* P = (float*)d_ws;   // exactly VOCAB*HID*4 = 25.6 MB (R1-proven)

    proj_persist<<<256, 512, 0, stream>>>(emb, Wih, bih, bhh, P);
    rnn_kernel<<<BATCH, 512, 0, stream>>>(x, Whh, P, fcw, fcb, (float*)d_out);
}